// Round 10
// baseline (165.533 us; speedup 1.0000x reference)
//
#include <hip/hip_runtime.h>
#include <hip/hip_fp16.h>

#define PI_F 3.14159265358979323846f

typedef __attribute__((ext_vector_type(8))) _Float16 f16x8;
typedef __attribute__((ext_vector_type(16))) float f32x16;
typedef __attribute__((ext_vector_type(2))) float v2f;

// ---------- packed-fp32 complex helpers (v_pk_fma_f32) ----------
__device__ __forceinline__ v2f pfma(v2f a, v2f b, v2f c) {
    return __builtin_elementwise_fma(a, b, c);
}
__device__ __forceinline__ v2f vswap(v2f a) { return __builtin_shufflevector(a, a, 1, 0); }
__device__ __forceinline__ v2f vsplat(float x) { v2f r; r.x = x; r.y = x; return r; }
__device__ __forceinline__ v2f mkc(v2f u) { v2f r; r.x = -u.y; r.y = u.y; return r; }
__device__ __forceinline__ v2f cmul(v2f a, v2f b) {
    return pfma(mkc(a), vswap(b), vsplat(a.x) * b);
}

__device__ __forceinline__ unsigned f2bf_rn(float x) {
    unsigned u = __float_as_uint(x);
    return (u + 0x7fffu + ((u >> 16) & 1u)) >> 16;
}

union H8 { int4 i4; f16x8 v; };
union U8 { int4 i4; unsigned short u[8]; };

// async global->LDS, 16B per lane; LDS dest = wave-uniform base + lane*16
__device__ __forceinline__ void gll16(const void* g, void* l) {
    __builtin_amdgcn_global_load_lds(
        (const __attribute__((address_space(1))) void*)g,
        (__attribute__((address_space(3))) void*)l, 16, 0, 0);
}

// ---------------- K1: encoder -> U3 -> MPS chain -> amp MFMA -> A[b] ----------------
// One block per batch b (sole writer of A[b] — cross-block striping of A[b] failed
// verification twice; do not reintroduce). 512 threads; L/R chains split across
// thread halves (neutral perf, kept for occupancy); swapped-operand amp MFMA with
// dwordx2 packed stores (round-6 win, -7 us).
struct PreLds {
    float xr[64]; float h[128]; float ang[96];
    v2f vL[32];            // a_p: vL[(15-p)*2 + s]
    v2f uL[64];            // G_p: uL[(15-p)*4 + z*2 + y]
    _Float16 lR[256*8];    // R rows (4 KB)
    _Float16 lL[512*8];    // L re-plane rows 0..255, im-plane 256..511 (8 KB)
};

__global__ __launch_bounds__(512) void k_pre(
        const float* __restrict__ x, const float* __restrict__ W1,
        const float* __restrict__ b1, const float* __restrict__ W2,
        const float* __restrict__ b2, const float* __restrict__ scaling,
        _Float16* __restrict__ A) {
    __shared__ PreLds lds;
    const int t = threadIdx.x;           // 0..511
    const int b = blockIdx.x;
    if (t < 64) lds.xr[t] = x[b*64 + t];
    __syncthreads();
    if (t < 128) {
        float acc = b1[t];
        #pragma unroll 8
        for (int f = 0; f < 64; ++f) acc = fmaf(lds.xr[f], W1[f*128 + t], acc);
        lds.h[t] = fmaxf(acc, 0.f);
    }
    __syncthreads();
    if (t < 96) {
        float acc = b2[t];
        #pragma unroll 8
        for (int f = 0; f < 128; ++f) acc = fmaf(lds.h[f], W2[f*96 + t], acc);
        int q = (t/3) & 15;
        lds.ang[t] = tanhf(acc) * scaling[q] * PI_F;
    }
    __syncthreads();
    if (t < 32) {
        int l = t >> 4, q = t & 15;
        const float* a = lds.ang + l*48 + q*3;
        float st, ct, sp, cp, sl, cl;
        sincosf(a[0]*0.5f, &st, &ct);
        sincosf(a[1]*0.5f, &sp, &cp);
        sincosf(a[2]*0.5f, &sl, &cl);
        float2 A00 = make_float2( cp*ct,  sp*st);
        float2 A01 = make_float2(-sp*ct, -cp*st);
        float2 A10 = make_float2( sp*ct, -cp*st);
        float2 A11 = make_float2( cp*ct, -sp*st);
        float2 e0 = make_float2(cl, -sl), e1 = make_float2(cl, sl);
        v2f r00; r00.x = e0.x*A00.x - e0.y*A00.y; r00.y = e0.x*A00.y + e0.y*A00.x;
        v2f r01; r01.x = e0.x*A01.x - e0.y*A01.y; r01.y = e0.x*A01.y + e0.y*A01.x;
        v2f r10; r10.x = e1.x*A10.x - e1.y*A10.y; r10.y = e1.x*A10.y + e1.y*A10.x;
        v2f r11; r11.x = e1.x*A11.x - e1.y*A11.y; r11.y = e1.x*A11.y + e1.y*A11.x;
        if (l == 0) {                 // layer-0: U|0> = column 0
            lds.vL[q*2 + 0] = r00;
            lds.vL[q*2 + 1] = r10;
        } else {                      // layer-1 gates, row-major
            lds.uL[q*4 + 0] = r00; lds.uL[q*4 + 1] = r01;
            lds.uL[q*4 + 2] = r10; lds.uL[q*4 + 3] = r11;
        }
    }
    __syncthreads();
    #define AP(p, s) lds.vL[(15-(p))*2 + (s)]
    #define GG(p, zv, yv) lds.uL[(15-(p))*4 + (zv)*2 + (yv)]
    {
        const float SL = 32.f;
        if (t < 256) {
            // ---- L-chain: thread t = prefix (z0..z7) ----
            v2f Lg[2][2];   // [g][y7]
            int z0 = t & 1, z1 = (t >> 1) & 1;
            #pragma unroll
            for (int g = 0; g < 2; ++g)
                #pragma unroll
                for (int y = 0; y < 2; ++y)
                    Lg[g][y] = cmul(cmul(GG(0, z0, g), AP(0, g ^ y)), GG(1, z1, y));
            #pragma unroll
            for (int p = 2; p <= 7; ++p) {
                int zp = (t >> p) & 1;
                #pragma unroll
                for (int g = 0; g < 2; ++g) {
                    v2f s0 = cmul(Lg[g][0], AP(p-1, 0)) + cmul(Lg[g][1], AP(p-1, 1));
                    v2f s1 = cmul(Lg[g][0], AP(p-1, 1)) + cmul(Lg[g][1], AP(p-1, 0));
                    Lg[g][0] = cmul(s0, GG(p, zp, 0));
                    Lg[g][1] = cmul(s1, GG(p, zp, 1));
                }
            }
            float lre[4] = {Lg[0][0].x, Lg[0][1].x, Lg[1][0].x, Lg[1][1].x};
            float lim[4] = {Lg[0][0].y, Lg[0][1].y, Lg[1][0].y, Lg[1][1].y};
            H8 hre, him;
            #pragma unroll
            for (int k = 0; k < 4; ++k) {
                hre.v[k]   = (_Float16)(SL * lre[k]);
                hre.v[4+k] = (_Float16)(-SL * lim[k]);
                him.v[k]   = (_Float16)(SL * lim[k]);
                him.v[4+k] = (_Float16)(SL * lre[k]);
            }
            *(int4*)&lds.lL[t*8]         = hre.i4;   // re-plane col
            *(int4*)&lds.lL[(256+t)*8]   = him.i4;   // im-plane col
        } else {
            // ---- R-chain: thread ts = suffix (z8..z15) ----
            const int ts = t - 256;
            v2f Rg[2][2];   // [g][y7]
            int z15 = (ts >> 7) & 1;
            #pragma unroll
            for (int g = 0; g < 2; ++g)
                #pragma unroll
                for (int y14 = 0; y14 < 2; ++y14)
                    Rg[g][y14] = cmul(cmul(AP(14, y14 ^ g),     AP(15, g)),     GG(15, z15, 0))
                               + cmul(cmul(AP(14, y14 ^ 1 ^ g), AP(15, 1 ^ g)), GG(15, z15, 1));
            #pragma unroll
            for (int p = 14; p >= 8; --p) {
                int zp = (ts >> (p - 8)) & 1;
                #pragma unroll
                for (int g = 0; g < 2; ++g) {
                    v2f t0 = cmul(GG(p, zp, 0), Rg[g][0]);
                    v2f t1 = cmul(GG(p, zp, 1), Rg[g][1]);
                    v2f n0 = cmul(AP(p-1, 0), t0) + cmul(AP(p-1, 1), t1);
                    v2f n1 = cmul(AP(p-1, 1), t0) + cmul(AP(p-1, 0), t1);
                    Rg[g][0] = n0; Rg[g][1] = n1;
                }
            }
            float rre[4] = {Rg[0][0].x, Rg[0][1].x, Rg[1][0].x, Rg[1][1].x};
            float rim[4] = {Rg[0][0].y, Rg[0][1].y, Rg[1][0].y, Rg[1][1].y};
            H8 hr;
            #pragma unroll
            for (int k = 0; k < 4; ++k) {
                hr.v[k]    = (_Float16)(SL * rre[k]);
                hr.v[4+k]  = (_Float16)(SL * rim[k]);
            }
            *(int4*)&lds.lR[ts*8] = hr.i4;
        }
    }
    #undef AP
    #undef GG
    __syncthreads();
    // ---- amp phase: D^T[zl][zh] = L @ R^T via swapped-operand MFMA (K=8 pad 16) ----
    // 8 waves, wave w -> row-group w (zh rows [w*32, w*32+32)); lane owns ONE zh row
    // (n = lane&31), regs span zl (m) -> 8B dwordx2 stores per q-quad.
    {
        const int wave = t >> 6, lane = t & 63, h2 = lane >> 5, l32 = lane & 31;
        f16x8 zf = {};
        _Float16* Aout = A + ((size_t)b << 16);
        const int zh0 = wave*32;
        f16x8 rf = h2 ? zf : *(const f16x8*)&lds.lR[(zh0 + l32)*8];
        _Float16* rowp = Aout + (size_t)(zh0 + l32)*256 + 4*h2;
        #pragma unroll
        for (int j = 0; j < 8; ++j) {
            f16x8 bre = h2 ? zf : *(const f16x8*)&lds.lL[(j*32 + l32)*8];
            f16x8 bim = h2 ? zf : *(const f16x8*)&lds.lL[(256 + j*32 + l32)*8];
            f32x16 zc = {};
            f32x16 dre = __builtin_amdgcn_mfma_f32_32x32x16_f16(bre, rf, zc, 0, 0, 0);
            f32x16 dim = __builtin_amdgcn_mfma_f32_32x32x16_f16(bim, rf, zc, 0, 0, 0);
            #pragma unroll
            for (int g = 0; g < 4; ++g) {
                union { _Float16 h4[4]; uint2 u2; } pk;
                #pragma unroll
                for (int i = 0; i < 4; ++i) {
                    int q = g*4 + i;
                    float p = fmaf(dre[q], dre[q], dim[q]*dim[q]) * 0.00390625f;  // 2^-8
                    pk.h4[i] = (_Float16)p;
                }
                // col = j*32 + 4*h2 + 8*g + i  (m = (q&3) + 8*(q>>2) + 4*h2)
                *(uint2*)(rowp + j*32 + 8*g) = pk.u2;
            }
        }
    }
}

// ---------------- K2: direct-Wd1 fp16 MFMA GEMM, split-K ----------------
// partial[m][ksg][n] (bf16) = A[m, ksg*1024:+1024] @ (Wd1*64)[ksg*1024:+1024, n]
// tile 256m x 32n x 1024k, BK=64; grid 512 = 64 ksg x 8 nh (co-resident, 2/CU).
// Wd1 (64 MB fp32) read exactly once; the 8 nh blocks of one ksg differ by 64 in
// blockIdx -> same id%8 -> same XCD -> the ksg's 512 KB A-slice is one HBM fetch
// per XCD (HBM A ~= 32 MB). partial shrinks 16 MB -> 8 MB (half the K-slices).
__global__ __launch_bounds__(512, 4) void k_gemm(
        const _Float16* __restrict__ A, const float* __restrict__ Wd1,
        unsigned short* __restrict__ partial) {
    __shared__ _Float16 lA[256*64];   // 32 KB: [m][64k], chunk c at c^(r&7)
    __shared__ _Float16 lB[32*64];    //  4 KB: [n][64k], chunk c at c^S(n), S(n)=((n>>3)&7)^(n&7)
    const int id = blockIdx.x;
    const int xcd = id & 7;
    const int ksg = xcd*8 + ((id >> 3) & 7);     // 0..63
    const int nh  = id >> 6;                     // 0..7
    const int k0 = ksg*1024, n0 = nh*32;
    const int tid = threadIdx.x;
    const int wave = tid >> 6, lane = tid & 63;  // 8 waves: wave w -> rows [w*32,+32)
    const int h = lane >> 5, l32 = lane & 31;
    // B staging: thread owns k-pair word kw (k=2kw,2kw+1), n-pair nc..nc+1
    const int kw = tid >> 4;                 // 0..31
    const int nc = (tid & 15) * 2;           // 0..30
    unsigned* lBw = (unsigned*)lB;           // word view: row stride 32 words
    f32x16 acc = {};
    for (int s = 0; s < 16; ++s) {
        const int kb = k0 + s*64;
        // ---- B: 2 float2 fp32 loads (rows kb+2kw, kb+2kw+1; 2 cols) ----
        const float* wsrc = Wd1 + (size_t)(kb + 2*kw)*256 + n0 + nc;
        float2 w0 = *(const float2*)(wsrc);
        float2 w1 = *(const float2*)(wsrc + 256);
        // ---- A: 4 gll16 per thread (32 KB tile) ----
        #pragma unroll
        for (int i = 0; i < 4; ++i) {
            int ia = wave*4 + i;             // 0..31
            int r = ia*8 + (lane >> 3);
            int cch = (lane & 7) ^ (r & 7);
            gll16(A + (size_t)r*65536 + kb + cch*8, &lA[ia*512]);
        }
        // ---- pack half2(k,k+1)*64 and write to swizzled [n][k] ----
        {
            float a0[2] = {w0.x, w0.y};
            float a1[2] = {w1.x, w1.y};
            #pragma unroll
            for (int j = 0; j < 2; ++j) {
                int n = nc + j;
                int S = ((n >> 3) & 7) ^ (n & 7);
                __half2 hh = __floats2half2_rn(a0[j]*64.f, a1[j]*64.f);
                unsigned u; __builtin_memcpy(&u, &hh, 4);
                lBw[n*32 + (((kw >> 2) ^ S) << 2) + (kw & 3)] = u;
            }
        }
        __syncthreads();
        #pragma unroll
        for (int kk = 0; kk < 4; ++kk) {
            const int ch = kk*2 + h;
            int rA = wave*32 + l32;
            f16x8 af = *(const f16x8*)&lA[rA*64 + ((ch ^ (rA & 7)) << 3)];
            int rB = l32;
            int SB = ((rB >> 3) & 7) ^ (rB & 7);
            f16x8 bf = *(const f16x8*)&lB[rB*64 + ((ch ^ SB) << 3)];
            acc = __builtin_amdgcn_mfma_f32_32x32x16_f16(af, bf, acc, 0, 0, 0);
        }
        __syncthreads();
    }
    // ---- epilogue: partial[m][ksg][n] bf16, [256][64][256] ----
    {
        int n = n0 + l32;
        int mb = wave*32 + 4*h;
        #pragma unroll
        for (int q = 0; q < 16; ++q) {
            int m = mb + (q & 3) + 8*(q >> 2);
            partial[((size_t)m*64 + ksg)*256 + n] = (unsigned short)f2bf_rn(acc[q]);
        }
    }
}

// ---------------- K3: fused reduce (64 ksg, x 2^-18) + bias + relu + GEMV ----
// partial[m] is one contiguous 32 KB block -> fully coalesced int4 stream.
// GEMV split across 4 thread-groups + LDS reduce.
__global__ __launch_bounds__(256) void k_final(
        const unsigned short* __restrict__ partial, const float* __restrict__ bd1,
        const float* __restrict__ Wd2, const float* __restrict__ bd2,
        float* __restrict__ out) {
    __shared__ float red[8][256];
    __shared__ float row[256];
    __shared__ float red2[4][64];
    const int m = blockIdx.x, t = threadIdx.x;
    const int o = t & 31, kg = t >> 5;       // n-octet, ksg-group (8 ksg each)
    {
        const unsigned short* p = partial + (size_t)m*16384 + kg*8*256 + o*8;
        float acc[8] = {0.f,0.f,0.f,0.f,0.f,0.f,0.f,0.f};
        #pragma unroll
        for (int i = 0; i < 8; ++i) {
            U8 v; v.i4 = *(const int4*)(p + (size_t)i*256);
            #pragma unroll
            for (int j = 0; j < 8; ++j)
                acc[j] += __uint_as_float(((unsigned)v.u[j]) << 16);
        }
        #pragma unroll
        for (int j = 0; j < 8; ++j) red[kg][o*8 + j] = acc[j];
    }
    __syncthreads();
    {
        float s = 0.f;
        #pragma unroll
        for (int g = 0; g < 8; ++g) s += red[g][t];
        const float SC = 1.f / 262144.f;   // undo 4096 (A) * 64 (Wd1 cvt)
        row[t] = fmaxf(fmaf(s, SC, bd1[t]), 0.f);
    }
    __syncthreads();
    {
        const int g = t >> 6, tt = t & 63;
        float o2 = 0.f;
        #pragma unroll 8
        for (int i = 0; i < 64; ++i) {
            int n = g*64 + i;
            o2 = fmaf(row[n], Wd2[n*64 + tt], o2);
        }
        red2[g][tt] = o2;
    }
    __syncthreads();
    if (t < 64) {
        float o3 = bd2[t] + ((red2[0][t] + red2[1][t]) + (red2[2][t] + red2[3][t]));
        out[m*64 + t] = fmaxf(o3, 0.f);
    }
}

extern "C" void kernel_launch(void* const* d_in, const int* in_sizes, int n_in,
                              void* d_out, int out_size, void* d_ws, size_t ws_size,
                              hipStream_t stream) {
    const float* x       = (const float*)d_in[0];
    const float* W1      = (const float*)d_in[1];
    const float* b1      = (const float*)d_in[2];
    const float* W2      = (const float*)d_in[3];
    const float* b2      = (const float*)d_in[4];
    const float* scaling = (const float*)d_in[5];
    const float* Wd1     = (const float*)d_in[6];
    const float* bd1     = (const float*)d_in[7];
    const float* Wd2     = (const float*)d_in[8];
    const float* bd2     = (const float*)d_in[9];
    float* out = (float*)d_out;

    char* ws = (char*)d_ws;
    const size_t MB = 1024*1024;
    _Float16* A  = (_Float16*)(ws + 4*MB);                    // 32 MB  [4,36)
    unsigned short* partial = (unsigned short*)(ws + 36*MB);  //  8 MB  [36,44)

    hipLaunchKernelGGL(k_pre, dim3(256), dim3(512), 0, stream,
                       x, W1, b1, W2, b2, scaling, A);
    hipLaunchKernelGGL(k_gemm, dim3(512), dim3(512), 0, stream, A, Wd1, partial);
    hipLaunchKernelGGL(k_final, dim3(256), dim3(256), 0, stream,
                       partial, bd1, Wd2, bd2, out);
}

// Round 11
// 160.916 us; speedup vs baseline: 1.0287x; 1.0287x over previous
//
#include <hip/hip_runtime.h>
#include <hip/hip_fp16.h>

#define PI_F 3.14159265358979323846f

typedef __attribute__((ext_vector_type(8))) _Float16 f16x8;
typedef __attribute__((ext_vector_type(16))) float f32x16;
typedef __attribute__((ext_vector_type(2))) float v2f;

// ---------- packed-fp32 complex helpers (v_pk_fma_f32) ----------
__device__ __forceinline__ v2f pfma(v2f a, v2f b, v2f c) {
    return __builtin_elementwise_fma(a, b, c);
}
__device__ __forceinline__ v2f vswap(v2f a) { return __builtin_shufflevector(a, a, 1, 0); }
__device__ __forceinline__ v2f vsplat(float x) { v2f r; r.x = x; r.y = x; return r; }
__device__ __forceinline__ v2f mkc(v2f u) { v2f r; r.x = -u.y; r.y = u.y; return r; }
__device__ __forceinline__ v2f cmul(v2f a, v2f b) {
    return pfma(mkc(a), vswap(b), vsplat(a.x) * b);
}

__device__ __forceinline__ unsigned f2bf_rn(float x) {
    unsigned u = __float_as_uint(x);
    return (u + 0x7fffu + ((u >> 16) & 1u)) >> 16;
}

union H8 { int4 i4; f16x8 v; };
union U8 { int4 i4; unsigned short u[8]; };

// async global->LDS, 16B per lane; LDS dest = wave-uniform base + lane*16
__device__ __forceinline__ void gll16(const void* g, void* l) {
    __builtin_amdgcn_global_load_lds(
        (const __attribute__((address_space(1))) void*)g,
        (__attribute__((address_space(3))) void*)l, 16, 0, 0);
}

// ---------------- K1: encoder -> U3 -> MPS chain -> amp MFMA -> A[b] ----------------
// One block per batch b (sole writer of A[b] — cross-block striping of A[b] failed
// verification twice; do not reintroduce). 512 threads: waves 0-3 run the exact
// t<256 encoder/chain/pack phases; all 8 waves run the amp phase (1 row-group each).
// Amp MFMA operands are SWAPPED (dot products are symmetric -> D^T, same values):
// per lane the 16 acc regs are 16 consecutive zl-columns of ONE zh-row, so q-quads
// pack into 8-byte dwordx2 stores: 32 store instrs/lane instead of 128 x 2B.
struct PreLds {
    float xr[64]; float h[128]; float ang[96];
    v2f vL[32];            // a_p: vL[(15-p)*2 + s]
    v2f uL[64];            // G_p: uL[(15-p)*4 + z*2 + y]
    _Float16 lR[256*8];    // R rows (4 KB)
    _Float16 lL[512*8];    // L re-plane rows 0..255, im-plane 256..511 (8 KB)
};

__global__ __launch_bounds__(512) void k_pre(
        const float* __restrict__ x, const float* __restrict__ W1,
        const float* __restrict__ b1, const float* __restrict__ W2,
        const float* __restrict__ b2, const float* __restrict__ scaling,
        _Float16* __restrict__ A) {
    __shared__ PreLds lds;
    const int t = threadIdx.x;           // 0..511
    const int b = blockIdx.x;
    if (t < 64) lds.xr[t] = x[b*64 + t];
    __syncthreads();
    if (t < 128) {
        float acc = b1[t];
        #pragma unroll 8
        for (int f = 0; f < 64; ++f) acc = fmaf(lds.xr[f], W1[f*128 + t], acc);
        lds.h[t] = fmaxf(acc, 0.f);
    }
    __syncthreads();
    if (t < 96) {
        float acc = b2[t];
        #pragma unroll 8
        for (int f = 0; f < 128; ++f) acc = fmaf(lds.h[f], W2[f*96 + t], acc);
        int q = (t/3) & 15;
        lds.ang[t] = tanhf(acc) * scaling[q] * PI_F;
    }
    __syncthreads();
    if (t < 32) {
        int l = t >> 4, q = t & 15;
        const float* a = lds.ang + l*48 + q*3;
        float st, ct, sp, cp, sl, cl;
        sincosf(a[0]*0.5f, &st, &ct);
        sincosf(a[1]*0.5f, &sp, &cp);
        sincosf(a[2]*0.5f, &sl, &cl);
        float2 A00 = make_float2( cp*ct,  sp*st);
        float2 A01 = make_float2(-sp*ct, -cp*st);
        float2 A10 = make_float2( sp*ct, -cp*st);
        float2 A11 = make_float2( cp*ct, -sp*st);
        float2 e0 = make_float2(cl, -sl), e1 = make_float2(cl, sl);
        v2f r00; r00.x = e0.x*A00.x - e0.y*A00.y; r00.y = e0.x*A00.y + e0.y*A00.x;
        v2f r01; r01.x = e0.x*A01.x - e0.y*A01.y; r01.y = e0.x*A01.y + e0.y*A01.x;
        v2f r10; r10.x = e1.x*A10.x - e1.y*A10.y; r10.y = e1.x*A10.y + e1.y*A10.x;
        v2f r11; r11.x = e1.x*A11.x - e1.y*A11.y; r11.y = e1.x*A11.y + e1.y*A11.x;
        if (l == 0) {                 // layer-0: U|0> = column 0
            lds.vL[q*2 + 0] = r00;
            lds.vL[q*2 + 1] = r10;
        } else {                      // layer-1 gates, row-major
            lds.uL[q*4 + 0] = r00; lds.uL[q*4 + 1] = r01;
            lds.uL[q*4 + 2] = r10; lds.uL[q*4 + 3] = r11;
        }
    }
    __syncthreads();
    if (t < 256) {
        // ---- chain phase: thread t = prefix (z0..z7) for L, suffix (z8..z15) for R ----
        #define AP(p, s) lds.vL[(15-(p))*2 + (s)]
        #define GG(p, zv, yv) lds.uL[(15-(p))*4 + (zv)*2 + (yv)]
        const float SL = 32.f;
        v2f Lg[2][2];   // [g][y7]
        {
            int z0 = t & 1, z1 = (t >> 1) & 1;
            #pragma unroll
            for (int g = 0; g < 2; ++g)
                #pragma unroll
                for (int y = 0; y < 2; ++y)
                    Lg[g][y] = cmul(cmul(GG(0, z0, g), AP(0, g ^ y)), GG(1, z1, y));
            #pragma unroll
            for (int p = 2; p <= 7; ++p) {
                int zp = (t >> p) & 1;
                #pragma unroll
                for (int g = 0; g < 2; ++g) {
                    v2f s0 = cmul(Lg[g][0], AP(p-1, 0)) + cmul(Lg[g][1], AP(p-1, 1));
                    v2f s1 = cmul(Lg[g][0], AP(p-1, 1)) + cmul(Lg[g][1], AP(p-1, 0));
                    Lg[g][0] = cmul(s0, GG(p, zp, 0));
                    Lg[g][1] = cmul(s1, GG(p, zp, 1));
                }
            }
        }
        v2f Rg[2][2];   // [g][y7]
        {
            int z15 = (t >> 7) & 1;
            #pragma unroll
            for (int g = 0; g < 2; ++g)
                #pragma unroll
                for (int y14 = 0; y14 < 2; ++y14)
                    Rg[g][y14] = cmul(cmul(AP(14, y14 ^ g),     AP(15, g)),     GG(15, z15, 0))
                               + cmul(cmul(AP(14, y14 ^ 1 ^ g), AP(15, 1 ^ g)), GG(15, z15, 1));
            #pragma unroll
            for (int p = 14; p >= 8; --p) {
                int zp = (t >> (p - 8)) & 1;
                #pragma unroll
                for (int g = 0; g < 2; ++g) {
                    v2f t0 = cmul(GG(p, zp, 0), Rg[g][0]);
                    v2f t1 = cmul(GG(p, zp, 1), Rg[g][1]);
                    v2f n0 = cmul(AP(p-1, 0), t0) + cmul(AP(p-1, 1), t1);
                    v2f n1 = cmul(AP(p-1, 1), t0) + cmul(AP(p-1, 0), t1);
                    Rg[g][0] = n0; Rg[g][1] = n1;
                }
            }
        }
        #undef AP
        #undef GG
        // ---- pack fp16 rows into LDS: k = g*2 + y7; B-operand signs prebaked ----
        {
            float lre[4] = {Lg[0][0].x, Lg[0][1].x, Lg[1][0].x, Lg[1][1].x};
            float lim[4] = {Lg[0][0].y, Lg[0][1].y, Lg[1][0].y, Lg[1][1].y};
            float rre[4] = {Rg[0][0].x, Rg[0][1].x, Rg[1][0].x, Rg[1][1].x};
            float rim[4] = {Rg[0][0].y, Rg[0][1].y, Rg[1][0].y, Rg[1][1].y};
            H8 hre, him, hr;
            #pragma unroll
            for (int k = 0; k < 4; ++k) {
                hre.v[k]   = (_Float16)(SL * lre[k]);
                hre.v[4+k] = (_Float16)(-SL * lim[k]);
                him.v[k]   = (_Float16)(SL * lim[k]);
                him.v[4+k] = (_Float16)(SL * lre[k]);
                hr.v[k]    = (_Float16)(SL * rre[k]);
                hr.v[4+k]  = (_Float16)(SL * rim[k]);
            }
            *(int4*)&lds.lR[t*8]         = hr.i4;
            *(int4*)&lds.lL[t*8]         = hre.i4;   // re-plane col
            *(int4*)&lds.lL[(256+t)*8]   = him.i4;   // im-plane col
        }
    }
    __syncthreads();
    // ---- amp phase: D^T[zl][zh] = L @ R^T via swapped-operand MFMA (K=8 pad 16) ----
    // 8 waves, wave w -> row-group w (zh rows [w*32, w*32+32)); lane owns ONE zh row
    // (n = lane&31), regs span zl (m) -> 8B dwordx2 stores per q-quad.
    {
        const int wave = t >> 6, lane = t & 63, h2 = lane >> 5, l32 = lane & 31;
        f16x8 zf = {};
        _Float16* Aout = A + ((size_t)b << 16);
        const int zh0 = wave*32;
        f16x8 rf = h2 ? zf : *(const f16x8*)&lds.lR[(zh0 + l32)*8];
        _Float16* rowp = Aout + (size_t)(zh0 + l32)*256 + 4*h2;
        #pragma unroll
        for (int j = 0; j < 8; ++j) {
            f16x8 bre = h2 ? zf : *(const f16x8*)&lds.lL[(j*32 + l32)*8];
            f16x8 bim = h2 ? zf : *(const f16x8*)&lds.lL[(256 + j*32 + l32)*8];
            f32x16 zc = {};
            f32x16 dre = __builtin_amdgcn_mfma_f32_32x32x16_f16(bre, rf, zc, 0, 0, 0);
            f32x16 dim = __builtin_amdgcn_mfma_f32_32x32x16_f16(bim, rf, zc, 0, 0, 0);
            #pragma unroll
            for (int g = 0; g < 4; ++g) {
                union { _Float16 h4[4]; uint2 u2; } pk;
                #pragma unroll
                for (int i = 0; i < 4; ++i) {
                    int q = g*4 + i;
                    float p = fmaf(dre[q], dre[q], dim[q]*dim[q]) * 0.00390625f;  // 2^-8
                    pk.h4[i] = (_Float16)p;
                }
                // col = j*32 + 4*h2 + 8*g + i  (m = (q&3) + 8*(q>>2) + 4*h2)
                *(uint2*)(rowp + j*32 + 8*g) = pk.u2;
            }
        }
    }
}

// ---------------- K2: direct-Wd1 fp16 MFMA GEMM, split-K ----------------
// partial[m][ksg][n] (bf16) = A[m, ksg*512:+512] @ (Wd1*64)[ksg*512:+512, n]
// tile 256m x 64n x 512k, BK=64; grid 512 = 128 ksg x 4 nh (all co-resident, 2/CU).
// Wd1 (64 MB fp32) read exactly once; the 4 nh blocks of one ksg share id%8 ->
// same XCD -> the ksg's 256 KB A-slice is fetched once per XCD (HBM A ~= 32 MB).
// K-slice sweep measured: K=256 -> 165.5, K=512 -> 158.5, K=1024 -> 165.5 us
// (K=1024: MfmaUtil 6.7%, 16% HBM — barrier/latency-bound; K=512 is the optimum).
__global__ __launch_bounds__(512, 4) void k_gemm(
        const _Float16* __restrict__ A, const float* __restrict__ Wd1,
        unsigned short* __restrict__ partial) {
    __shared__ _Float16 lA[256*64];   // 32 KB: [m][64k], chunk c at c^(r&7)
    __shared__ _Float16 lB[64*64];    //  8 KB: [n][64k], chunk c at c^S(n), S(n)=((n>>3)&7)^(n&7)
    const int id = blockIdx.x;
    const int xcd = id & 7;
    const int ksg = xcd*16 + ((id >> 3) & 15);   // 0..127
    const int nh  = id >> 7;                     // 0..3
    const int k0 = ksg*512, n0 = nh*64;
    const int tid = threadIdx.x;
    const int wave = tid >> 6, lane = tid & 63;
    const int mw = wave >> 1, nw = wave & 1;     // 4m x 2n wave grid: 64m x 32n each
    const int h = lane >> 5, l32 = lane & 31;
    // B staging: thread owns k-pair word kw (k=2kw,2kw+1), n-quad nc4..nc4+3
    const int kw = tid >> 4;                 // 0..31
    const int nc4 = (tid & 15) * 4;          // 0..60
    unsigned* lBw = (unsigned*)lB;           // word view: row stride 32 words
    f32x16 acc[2] = {};
    for (int s = 0; s < 8; ++s) {
        const int kb = k0 + s*64;
        // ---- B: 2 float4 fp32 loads (rows kb+2kw, kb+2kw+1) ----
        const float* wsrc = Wd1 + (size_t)(kb + 2*kw)*256 + n0 + nc4;
        float4 w0 = *(const float4*)(wsrc);
        float4 w1 = *(const float4*)(wsrc + 256);
        // ---- A: 4 gll16 per thread (32 KB tile) ----
        #pragma unroll
        for (int i = 0; i < 4; ++i) {
            int ia = wave*4 + i;             // 0..31
            int r = ia*8 + (lane >> 3);
            int cch = (lane & 7) ^ (r & 7);
            gll16(A + (size_t)r*65536 + kb + cch*8, &lA[ia*512]);
        }
        // ---- pack half2(k,k+1)*64 and write to swizzled [n][k] ----
        {
            float a0[4] = {w0.x,w0.y,w0.z,w0.w};
            float a1[4] = {w1.x,w1.y,w1.z,w1.w};
            #pragma unroll
            for (int j = 0; j < 4; ++j) {
                int n = nc4 + j;
                int S = ((n >> 3) & 7) ^ (n & 7);
                __half2 hh = __floats2half2_rn(a0[j]*64.f, a1[j]*64.f);
                unsigned u; __builtin_memcpy(&u, &hh, 4);
                lBw[n*32 + (((kw >> 2) ^ S) << 2) + (kw & 3)] = u;
            }
        }
        __syncthreads();
        #pragma unroll
        for (int kk = 0; kk < 4; ++kk) {
            const int ch = kk*2 + h;
            f16x8 af[2], bf;
            #pragma unroll
            for (int xx = 0; xx < 2; ++xx) {
                int rA = mw*64 + xx*32 + l32;
                af[xx] = *(const f16x8*)&lA[rA*64 + ((ch ^ (rA & 7)) << 3)];
            }
            int rB = nw*32 + l32;
            int SB = ((rB >> 3) & 7) ^ (rB & 7);
            bf = *(const f16x8*)&lB[rB*64 + ((ch ^ SB) << 3)];
            #pragma unroll
            for (int i = 0; i < 2; ++i)
                acc[i] = __builtin_amdgcn_mfma_f32_32x32x16_f16(af[i], bf, acc[i], 0, 0, 0);
        }
        __syncthreads();
    }
    // ---- epilogue: partial[m][ksg][n] bf16, [256][128][256] ----
    #pragma unroll
    for (int i = 0; i < 2; ++i) {
        int n = n0 + nw*32 + l32;
        int mb = mw*64 + i*32 + 4*h;
        #pragma unroll
        for (int q = 0; q < 16; ++q) {
            int m = mb + (q & 3) + 8*(q >> 2);
            partial[((size_t)m*128 + ksg)*256 + n] = (unsigned short)f2bf_rn(acc[i][q]);
        }
    }
}

// ---------------- K3: fused reduce (128 ksg, x 2^-18) + bias + relu + GEMV ----
// partial[m] is one contiguous 64 KB block -> fully coalesced int4 stream.
// GEMV split across 4 thread-groups (was 64/256 threads active) + LDS reduce.
__global__ __launch_bounds__(256) void k_final(
        const unsigned short* __restrict__ partial, const float* __restrict__ bd1,
        const float* __restrict__ Wd2, const float* __restrict__ bd2,
        float* __restrict__ out) {
    __shared__ float red[8][256];
    __shared__ float row[256];
    __shared__ float red2[4][64];
    const int m = blockIdx.x, t = threadIdx.x;
    const int o = t & 31, kg = t >> 5;       // n-octet, ksg-group (16 ksg each)
    {
        const unsigned short* p = partial + (size_t)m*32768 + kg*16*256 + o*8;
        float acc[8] = {0.f,0.f,0.f,0.f,0.f,0.f,0.f,0.f};
        #pragma unroll 8
        for (int i = 0; i < 16; ++i) {
            U8 v; v.i4 = *(const int4*)(p + (size_t)i*256);
            #pragma unroll
            for (int j = 0; j < 8; ++j)
                acc[j] += __uint_as_float(((unsigned)v.u[j]) << 16);
        }
        #pragma unroll
        for (int j = 0; j < 8; ++j) red[kg][o*8 + j] = acc[j];
    }
    __syncthreads();
    {
        float s = 0.f;
        #pragma unroll
        for (int g = 0; g < 8; ++g) s += red[g][t];
        const float SC = 1.f / 262144.f;   // undo 4096 (A) * 64 (Wd1 cvt)
        row[t] = fmaxf(fmaf(s, SC, bd1[t]), 0.f);
    }
    __syncthreads();
    {
        const int g = t >> 6, tt = t & 63;
        float o2 = 0.f;
        #pragma unroll 8
        for (int i = 0; i < 64; ++i) {
            int n = g*64 + i;
            o2 = fmaf(row[n], Wd2[n*64 + tt], o2);
        }
        red2[g][tt] = o2;
    }
    __syncthreads();
    if (t < 64) {
        float o3 = bd2[t] + ((red2[0][t] + red2[1][t]) + (red2[2][t] + red2[3][t]));
        out[m*64 + t] = fmaxf(o3, 0.f);
    }
}

extern "C" void kernel_launch(void* const* d_in, const int* in_sizes, int n_in,
                              void* d_out, int out_size, void* d_ws, size_t ws_size,
                              hipStream_t stream) {
    const float* x       = (const float*)d_in[0];
    const float* W1      = (const float*)d_in[1];
    const float* b1      = (const float*)d_in[2];
    const float* W2      = (const float*)d_in[3];
    const float* b2      = (const float*)d_in[4];
    const float* scaling = (const float*)d_in[5];
    const float* Wd1     = (const float*)d_in[6];
    const float* bd1     = (const float*)d_in[7];
    const float* Wd2     = (const float*)d_in[8];
    const float* bd2     = (const float*)d_in[9];
    float* out = (float*)d_out;

    char* ws = (char*)d_ws;
    const size_t MB = 1024*1024;
    _Float16* A  = (_Float16*)(ws + 4*MB);                    // 32 MB  [4,36)
    unsigned short* partial = (unsigned short*)(ws + 36*MB);  // 16 MB  [36,52)

    hipLaunchKernelGGL(k_pre, dim3(256), dim3(512), 0, stream,
                       x, W1, b1, W2, b2, scaling, A);
    hipLaunchKernelGGL(k_gemm, dim3(512), dim3(512), 0, stream, A, Wd1, partial);
    hipLaunchKernelGGL(k_final, dim3(256), dim3(256), 0, stream,
                       partial, bd1, Wd2, bd2, out);
}

// Round 12
// 158.307 us; speedup vs baseline: 1.0456x; 1.0165x over previous
//
#include <hip/hip_runtime.h>
#include <hip/hip_fp16.h>

#define PI_F 3.14159265358979323846f

typedef __attribute__((ext_vector_type(8))) _Float16 f16x8;
typedef __attribute__((ext_vector_type(16))) float f32x16;
typedef __attribute__((ext_vector_type(2))) float v2f;

// ---------- packed-fp32 complex helpers (v_pk_fma_f32) ----------
__device__ __forceinline__ v2f pfma(v2f a, v2f b, v2f c) {
    return __builtin_elementwise_fma(a, b, c);
}
__device__ __forceinline__ v2f vswap(v2f a) { return __builtin_shufflevector(a, a, 1, 0); }
__device__ __forceinline__ v2f vsplat(float x) { v2f r; r.x = x; r.y = x; return r; }
__device__ __forceinline__ v2f mkc(v2f u) { v2f r; r.x = -u.y; r.y = u.y; return r; }
__device__ __forceinline__ v2f cmul(v2f a, v2f b) {
    return pfma(mkc(a), vswap(b), vsplat(a.x) * b);
}

__device__ __forceinline__ unsigned f2bf_rn(float x) {
    unsigned u = __float_as_uint(x);
    return (u + 0x7fffu + ((u >> 16) & 1u)) >> 16;
}

union H8 { int4 i4; f16x8 v; };
union U8 { int4 i4; unsigned short u[8]; };

// async global->LDS, 16B per lane; LDS dest = wave-uniform base + lane*16
__device__ __forceinline__ void gll16(const void* g, void* l) {
    __builtin_amdgcn_global_load_lds(
        (const __attribute__((address_space(1))) void*)g,
        (__attribute__((address_space(3))) void*)l, 16, 0, 0);
}

// ---------------- K1: encoder -> U3 -> MPS chain -> amp MFMA -> A[b] ----------------
// One block per batch b (sole writer of A[b] — cross-block striping of A[b] failed
// verification twice; do not reintroduce). 512 threads.
// Round-11 profile: k_pre was 42 us, 10% HBM, 93% stalled — the amp stores (8B per
// lane at 512B row stride = 25% cache-line utilization) drained at 0.78 TB/s.
// Fix: all 8 waves compute pk quads into REGISTERS, then 4 passes stage 64 rows
// (32 KB) into XOR-swizzled LDS and emit fully-linear dwordx4 global stores.
struct PreLds {
    float xr[64]; float h[128]; float ang[96];
    v2f vL[32];            // a_p: vL[(15-p)*2 + s]
    v2f uL[64];            // G_p: uL[(15-p)*4 + z*2 + y]
    _Float16 lR[256*8];    // R rows (4 KB)
    _Float16 lL[512*8];    // L re-plane rows 0..255, im-plane 256..511 (8 KB)
};

__global__ __launch_bounds__(512) void k_pre(
        const float* __restrict__ x, const float* __restrict__ W1,
        const float* __restrict__ b1, const float* __restrict__ W2,
        const float* __restrict__ b2, const float* __restrict__ scaling,
        _Float16* __restrict__ A) {
    __shared__ PreLds lds;
    __shared__ uint2 stg[64*64];         // 32 KB store-coalescing stage (64 rows)
    const int t = threadIdx.x;           // 0..511
    const int b = blockIdx.x;
    if (t < 64) lds.xr[t] = x[b*64 + t];
    __syncthreads();
    if (t < 128) {
        float acc = b1[t];
        #pragma unroll 8
        for (int f = 0; f < 64; ++f) acc = fmaf(lds.xr[f], W1[f*128 + t], acc);
        lds.h[t] = fmaxf(acc, 0.f);
    }
    __syncthreads();
    if (t < 96) {
        float acc = b2[t];
        #pragma unroll 8
        for (int f = 0; f < 128; ++f) acc = fmaf(lds.h[f], W2[f*96 + t], acc);
        int q = (t/3) & 15;
        lds.ang[t] = tanhf(acc) * scaling[q] * PI_F;
    }
    __syncthreads();
    if (t < 32) {
        int l = t >> 4, q = t & 15;
        const float* a = lds.ang + l*48 + q*3;
        float st, ct, sp, cp, sl, cl;
        sincosf(a[0]*0.5f, &st, &ct);
        sincosf(a[1]*0.5f, &sp, &cp);
        sincosf(a[2]*0.5f, &sl, &cl);
        float2 A00 = make_float2( cp*ct,  sp*st);
        float2 A01 = make_float2(-sp*ct, -cp*st);
        float2 A10 = make_float2( sp*ct, -cp*st);
        float2 A11 = make_float2( cp*ct, -sp*st);
        float2 e0 = make_float2(cl, -sl), e1 = make_float2(cl, sl);
        v2f r00; r00.x = e0.x*A00.x - e0.y*A00.y; r00.y = e0.x*A00.y + e0.y*A00.x;
        v2f r01; r01.x = e0.x*A01.x - e0.y*A01.y; r01.y = e0.x*A01.y + e0.y*A01.x;
        v2f r10; r10.x = e1.x*A10.x - e1.y*A10.y; r10.y = e1.x*A10.y + e1.y*A10.x;
        v2f r11; r11.x = e1.x*A11.x - e1.y*A11.y; r11.y = e1.x*A11.y + e1.y*A11.x;
        if (l == 0) {                 // layer-0: U|0> = column 0
            lds.vL[q*2 + 0] = r00;
            lds.vL[q*2 + 1] = r10;
        } else {                      // layer-1 gates, row-major
            lds.uL[q*4 + 0] = r00; lds.uL[q*4 + 1] = r01;
            lds.uL[q*4 + 2] = r10; lds.uL[q*4 + 3] = r11;
        }
    }
    __syncthreads();
    if (t < 256) {
        // ---- chain phase: thread t = prefix (z0..z7) for L, suffix (z8..z15) for R ----
        #define AP(p, s) lds.vL[(15-(p))*2 + (s)]
        #define GG(p, zv, yv) lds.uL[(15-(p))*4 + (zv)*2 + (yv)]
        const float SL = 32.f;
        v2f Lg[2][2];   // [g][y7]
        {
            int z0 = t & 1, z1 = (t >> 1) & 1;
            #pragma unroll
            for (int g = 0; g < 2; ++g)
                #pragma unroll
                for (int y = 0; y < 2; ++y)
                    Lg[g][y] = cmul(cmul(GG(0, z0, g), AP(0, g ^ y)), GG(1, z1, y));
            #pragma unroll
            for (int p = 2; p <= 7; ++p) {
                int zp = (t >> p) & 1;
                #pragma unroll
                for (int g = 0; g < 2; ++g) {
                    v2f s0 = cmul(Lg[g][0], AP(p-1, 0)) + cmul(Lg[g][1], AP(p-1, 1));
                    v2f s1 = cmul(Lg[g][0], AP(p-1, 1)) + cmul(Lg[g][1], AP(p-1, 0));
                    Lg[g][0] = cmul(s0, GG(p, zp, 0));
                    Lg[g][1] = cmul(s1, GG(p, zp, 1));
                }
            }
        }
        v2f Rg[2][2];   // [g][y7]
        {
            int z15 = (t >> 7) & 1;
            #pragma unroll
            for (int g = 0; g < 2; ++g)
                #pragma unroll
                for (int y14 = 0; y14 < 2; ++y14)
                    Rg[g][y14] = cmul(cmul(AP(14, y14 ^ g),     AP(15, g)),     GG(15, z15, 0))
                               + cmul(cmul(AP(14, y14 ^ 1 ^ g), AP(15, 1 ^ g)), GG(15, z15, 1));
            #pragma unroll
            for (int p = 14; p >= 8; --p) {
                int zp = (t >> (p - 8)) & 1;
                #pragma unroll
                for (int g = 0; g < 2; ++g) {
                    v2f t0 = cmul(GG(p, zp, 0), Rg[g][0]);
                    v2f t1 = cmul(GG(p, zp, 1), Rg[g][1]);
                    v2f n0 = cmul(AP(p-1, 0), t0) + cmul(AP(p-1, 1), t1);
                    v2f n1 = cmul(AP(p-1, 1), t0) + cmul(AP(p-1, 0), t1);
                    Rg[g][0] = n0; Rg[g][1] = n1;
                }
            }
        }
        #undef AP
        #undef GG
        // ---- pack fp16 rows into LDS: k = g*2 + y7; B-operand signs prebaked ----
        {
            float lre[4] = {Lg[0][0].x, Lg[0][1].x, Lg[1][0].x, Lg[1][1].x};
            float lim[4] = {Lg[0][0].y, Lg[0][1].y, Lg[1][0].y, Lg[1][1].y};
            float rre[4] = {Rg[0][0].x, Rg[0][1].x, Rg[1][0].x, Rg[1][1].x};
            float rim[4] = {Rg[0][0].y, Rg[0][1].y, Rg[1][0].y, Rg[1][1].y};
            H8 hre, him, hr;
            #pragma unroll
            for (int k = 0; k < 4; ++k) {
                hre.v[k]   = (_Float16)(SL * lre[k]);
                hre.v[4+k] = (_Float16)(-SL * lim[k]);
                him.v[k]   = (_Float16)(SL * lim[k]);
                him.v[4+k] = (_Float16)(SL * lre[k]);
                hr.v[k]    = (_Float16)(SL * rre[k]);
                hr.v[4+k]  = (_Float16)(SL * rim[k]);
            }
            *(int4*)&lds.lR[t*8]         = hr.i4;
            *(int4*)&lds.lL[t*8]         = hre.i4;   // re-plane col
            *(int4*)&lds.lL[(256+t)*8]   = him.i4;   // im-plane col
        }
    }
    __syncthreads();
    // ---- amp phase: D^T[zl][zh] = L @ R^T via swapped-operand MFMA (K=8 pad 16) ----
    // All 8 waves compute pk quads into registers: quad (j,g) of lane (l32,h2) =
    // row zh0+l32, cols j*32 + 4*h2 + 8*g + [0,4).
    const int wave = t >> 6, lane = t & 63, h2 = lane >> 5, l32 = lane & 31;
    uint2 pk[8][4];
    {
        f16x8 zf = {};
        const int zh0 = wave*32;
        f16x8 rf = h2 ? zf : *(const f16x8*)&lds.lR[(zh0 + l32)*8];
        #pragma unroll
        for (int j = 0; j < 8; ++j) {
            f16x8 bre = h2 ? zf : *(const f16x8*)&lds.lL[(j*32 + l32)*8];
            f16x8 bim = h2 ? zf : *(const f16x8*)&lds.lL[(256 + j*32 + l32)*8];
            f32x16 zc = {};
            f32x16 dre = __builtin_amdgcn_mfma_f32_32x32x16_f16(bre, rf, zc, 0, 0, 0);
            f32x16 dim = __builtin_amdgcn_mfma_f32_32x32x16_f16(bim, rf, zc, 0, 0, 0);
            #pragma unroll
            for (int g = 0; g < 4; ++g) {
                union { _Float16 h4[4]; uint2 u2; } w2;
                #pragma unroll
                for (int i = 0; i < 4; ++i) {
                    int q = g*4 + i;
                    float pv = fmaf(dre[q], dre[q], dim[q]*dim[q]) * 0.00390625f;  // 2^-8
                    w2.h4[i] = (_Float16)pv;
                }
                pk[j][g] = w2.u2;
            }
        }
    }
    // ---- staged coalesced writeback: 4 passes x 64 rows via 32 KB LDS ----
    // quad index within row: qi = j*8 + 2*g + h2; LDS slot = rloc*64 + (qi ^ sw),
    // sw = (rloc&7)<<1 (preserves bit0 -> 16B read contiguity; 4-way banks = 1.58x).
    {
        uint4* A16 = (uint4*)(A + ((size_t)b << 16));   // 8192 x 16B
        #pragma unroll
        for (int p = 0; p < 4; ++p) {
            if ((wave >> 1) == p) {
                const int rloc = (wave & 1)*32 + l32;
                const int sw = (rloc & 7) << 1;
                #pragma unroll
                for (int j = 0; j < 8; ++j)
                    #pragma unroll
                    for (int g = 0; g < 4; ++g) {
                        int qi = j*8 + 2*g + h2;
                        stg[rloc*64 + (qi ^ sw)] = pk[j][g];
                    }
            }
            __syncthreads();
            #pragma unroll
            for (int it = 0; it < 4; ++it) {
                int c = it*512 + t;              // 16B chunk within pass
                int rloc = c >> 5;               // 0..63
                int qi0 = (2*c) & 63;            // even quad index
                int qs = qi0 ^ ((rloc & 7) << 1);
                uint4 v = *(const uint4*)&stg[rloc*64 + qs];
                A16[p*2048 + c] = v;             // fully linear across threads
            }
            __syncthreads();
        }
    }
}

// ---------------- K2: direct-Wd1 fp16 MFMA GEMM, split-K ----------------
// partial[m][ksg][n] (bf16) = A[m, ksg*512:+512] @ (Wd1*64)[ksg*512:+512, n]
// tile 256m x 64n x 512k, BK=64; grid 512 = 128 ksg x 4 nh (all co-resident, 2/CU).
// Wd1 (64 MB fp32) read exactly once; the 4 nh blocks of one ksg share id%8 ->
// same XCD -> the ksg's 256 KB A-slice is fetched once per XCD (HBM A ~= 32 MB).
// K-slice sweep measured: K=256 -> 165.5, K=512 -> 158.5, K=1024 -> 165.5 us
// (K=1024: MfmaUtil 6.7%, 16% HBM — barrier/latency-bound; K=512 is the optimum).
__global__ __launch_bounds__(512, 4) void k_gemm(
        const _Float16* __restrict__ A, const float* __restrict__ Wd1,
        unsigned short* __restrict__ partial) {
    __shared__ _Float16 lA[256*64];   // 32 KB: [m][64k], chunk c at c^(r&7)
    __shared__ _Float16 lB[64*64];    //  8 KB: [n][64k], chunk c at c^S(n), S(n)=((n>>3)&7)^(n&7)
    const int id = blockIdx.x;
    const int xcd = id & 7;
    const int ksg = xcd*16 + ((id >> 3) & 15);   // 0..127
    const int nh  = id >> 7;                     // 0..3
    const int k0 = ksg*512, n0 = nh*64;
    const int tid = threadIdx.x;
    const int wave = tid >> 6, lane = tid & 63;
    const int mw = wave >> 1, nw = wave & 1;     // 4m x 2n wave grid: 64m x 32n each
    const int h = lane >> 5, l32 = lane & 31;
    // B staging: thread owns k-pair word kw (k=2kw,2kw+1), n-quad nc4..nc4+3
    const int kw = tid >> 4;                 // 0..31
    const int nc4 = (tid & 15) * 4;          // 0..60
    unsigned* lBw = (unsigned*)lB;           // word view: row stride 32 words
    f32x16 acc[2] = {};
    for (int s = 0; s < 8; ++s) {
        const int kb = k0 + s*64;
        // ---- B: 2 float4 fp32 loads (rows kb+2kw, kb+2kw+1) ----
        const float* wsrc = Wd1 + (size_t)(kb + 2*kw)*256 + n0 + nc4;
        float4 w0 = *(const float4*)(wsrc);
        float4 w1 = *(const float4*)(wsrc + 256);
        // ---- A: 4 gll16 per thread (32 KB tile) ----
        #pragma unroll
        for (int i = 0; i < 4; ++i) {
            int ia = wave*4 + i;             // 0..31
            int r = ia*8 + (lane >> 3);
            int cch = (lane & 7) ^ (r & 7);
            gll16(A + (size_t)r*65536 + kb + cch*8, &lA[ia*512]);
        }
        // ---- pack half2(k,k+1)*64 and write to swizzled [n][k] ----
        {
            float a0[4] = {w0.x,w0.y,w0.z,w0.w};
            float a1[4] = {w1.x,w1.y,w1.z,w1.w};
            #pragma unroll
            for (int j = 0; j < 4; ++j) {
                int n = nc4 + j;
                int S = ((n >> 3) & 7) ^ (n & 7);
                __half2 hh = __floats2half2_rn(a0[j]*64.f, a1[j]*64.f);
                unsigned u; __builtin_memcpy(&u, &hh, 4);
                lBw[n*32 + (((kw >> 2) ^ S) << 2) + (kw & 3)] = u;
            }
        }
        __syncthreads();
        #pragma unroll
        for (int kk = 0; kk < 4; ++kk) {
            const int ch = kk*2 + h;
            f16x8 af[2], bf;
            #pragma unroll
            for (int xx = 0; xx < 2; ++xx) {
                int rA = mw*64 + xx*32 + l32;
                af[xx] = *(const f16x8*)&lA[rA*64 + ((ch ^ (rA & 7)) << 3)];
            }
            int rB = nw*32 + l32;
            int SB = ((rB >> 3) & 7) ^ (rB & 7);
            bf = *(const f16x8*)&lB[rB*64 + ((ch ^ SB) << 3)];
            #pragma unroll
            for (int i = 0; i < 2; ++i)
                acc[i] = __builtin_amdgcn_mfma_f32_32x32x16_f16(af[i], bf, acc[i], 0, 0, 0);
        }
        __syncthreads();
    }
    // ---- epilogue: partial[m][ksg][n] bf16, [256][128][256] ----
    #pragma unroll
    for (int i = 0; i < 2; ++i) {
        int n = n0 + nw*32 + l32;
        int mb = mw*64 + i*32 + 4*h;
        #pragma unroll
        for (int q = 0; q < 16; ++q) {
            int m = mb + (q & 3) + 8*(q >> 2);
            partial[((size_t)m*128 + ksg)*256 + n] = (unsigned short)f2bf_rn(acc[i][q]);
        }
    }
}

// ---------------- K3: fused reduce (128 ksg, x 2^-18) + bias + relu + GEMV ----
// partial[m] is one contiguous 64 KB block -> fully coalesced int4 stream.
// GEMV split across 4 thread-groups (was 64/256 threads active) + LDS reduce.
__global__ __launch_bounds__(256) void k_final(
        const unsigned short* __restrict__ partial, const float* __restrict__ bd1,
        const float* __restrict__ Wd2, const float* __restrict__ bd2,
        float* __restrict__ out) {
    __shared__ float red[8][256];
    __shared__ float row[256];
    __shared__ float red2[4][64];
    const int m = blockIdx.x, t = threadIdx.x;
    const int o = t & 31, kg = t >> 5;       // n-octet, ksg-group (16 ksg each)
    {
        const unsigned short* p = partial + (size_t)m*32768 + kg*16*256 + o*8;
        float acc[8] = {0.f,0.f,0.f,0.f,0.f,0.f,0.f,0.f};
        #pragma unroll 8
        for (int i = 0; i < 16; ++i) {
            U8 v; v.i4 = *(const int4*)(p + (size_t)i*256);
            #pragma unroll
            for (int j = 0; j < 8; ++j)
                acc[j] += __uint_as_float(((unsigned)v.u[j]) << 16);
        }
        #pragma unroll
        for (int j = 0; j < 8; ++j) red[kg][o*8 + j] = acc[j];
    }
    __syncthreads();
    {
        float s = 0.f;
        #pragma unroll
        for (int g = 0; g < 8; ++g) s += red[g][t];
        const float SC = 1.f / 262144.f;   // undo 4096 (A) * 64 (Wd1 cvt)
        row[t] = fmaxf(fmaf(s, SC, bd1[t]), 0.f);
    }
    __syncthreads();
    {
        const int g = t >> 6, tt = t & 63;
        float o2 = 0.f;
        #pragma unroll 8
        for (int i = 0; i < 64; ++i) {
            int n = g*64 + i;
            o2 = fmaf(row[n], Wd2[n*64 + tt], o2);
        }
        red2[g][tt] = o2;
    }
    __syncthreads();
    if (t < 64) {
        float o3 = bd2[t] + ((red2[0][t] + red2[1][t]) + (red2[2][t] + red2[3][t]));
        out[m*64 + t] = fmaxf(o3, 0.f);
    }
}

extern "C" void kernel_launch(void* const* d_in, const int* in_sizes, int n_in,
                              void* d_out, int out_size, void* d_ws, size_t ws_size,
                              hipStream_t stream) {
    const float* x       = (const float*)d_in[0];
    const float* W1      = (const float*)d_in[1];
    const float* b1      = (const float*)d_in[2];
    const float* W2      = (const float*)d_in[3];
    const float* b2      = (const float*)d_in[4];
    const float* scaling = (const float*)d_in[5];
    const float* Wd1     = (const float*)d_in[6];
    const float* bd1     = (const float*)d_in[7];
    const float* Wd2     = (const float*)d_in[8];
    const float* bd2     = (const float*)d_in[9];
    float* out = (float*)d_out;

    char* ws = (char*)d_ws;
    const size_t MB = 1024*1024;
    _Float16* A  = (_Float16*)(ws + 4*MB);                    // 32 MB  [4,36)
    unsigned short* partial = (unsigned short*)(ws + 36*MB);  // 16 MB  [36,52)

    hipLaunchKernelGGL(k_pre, dim3(256), dim3(512), 0, stream,
                       x, W1, b1, W2, b2, scaling, A);
    hipLaunchKernelGGL(k_gemm, dim3(512), dim3(512), 0, stream, A, Wd1, partial);
    hipLaunchKernelGGL(k_final, dim3(256), dim3(256), 0, stream,
                       partial, bd1, Wd2, bd2, out);
}